// Round 1
// baseline (843.453 us; speedup 1.0000x reference)
//
#include <hip/hip_runtime.h>
#include <math.h>

#define BATCH 2
#define SEQ 1024
#define DM 512
#define DI 1024
#define DS 128
#define NH 16
#define HD 64
#define CONVD 1280
#define DPROJ 2320
#define ROWS (BATCH*SEQ)   // 2048

// ---------------- Kernel 1: in_proj GEMM ----------------
// zx[m][e] = sum_k x[m][k] * W[e][k],  m in [0,2048), e in [0,2320), k in [0,512)
// Each thread: one e, 8 m-rows (x loads are wave-uniform -> scalar loads).
__global__ __launch_bounds__(64) void k_in_proj(const float* __restrict__ x,
                                                const float* __restrict__ W,
                                                float* __restrict__ out) {
    int e  = blockIdx.x * 64 + threadIdx.x;
    int m0 = blockIdx.y * 8;
    if (e >= DPROJ) return;
    const float4* wr = reinterpret_cast<const float4*>(W + (size_t)e * DM);
    float acc[8] = {0.f,0.f,0.f,0.f,0.f,0.f,0.f,0.f};
    for (int k = 0; k < DM/4; ++k) {
        float4 w = wr[k];
        #pragma unroll
        for (int i = 0; i < 8; ++i) {
            float4 xv = *reinterpret_cast<const float4*>(x + (size_t)(m0+i)*DM + k*4);
            acc[i] += xv.x*w.x + xv.y*w.y + xv.z*w.z + xv.w*w.w;
        }
    }
    #pragma unroll
    for (int i = 0; i < 8; ++i)
        out[(size_t)(m0+i)*DPROJ + e] = acc[i];
}

// ---------------- Kernel 2: depthwise conv + SiLU, plus dt/dA ----------------
// convo[b][l][c] = silu(conv_b[c] + sum_k zx[b][l-3+k][DI+c]*conv_w[c][k])
__global__ __launch_bounds__(320) void k_conv(const float* __restrict__ zx,
                                              const float* __restrict__ cw,
                                              const float* __restrict__ cb,
                                              const float* __restrict__ dt_bias,
                                              const float* __restrict__ A_log,
                                              float* __restrict__ convo,
                                              float* __restrict__ dtb,
                                              float* __restrict__ dAb) {
    int row = blockIdx.x;            // b*SEQ + l
    int l   = row & (SEQ-1);
    int c0  = threadIdx.x * 4;

    const float4* cw4 = reinterpret_cast<const float4*>(cw);
    float4 w0 = cw4[c0+0], w1 = cw4[c0+1], w2 = cw4[c0+2], w3 = cw4[c0+3];
    const float* wa0 = &w0.x; const float* wa1 = &w1.x;
    const float* wa2 = &w2.x; const float* wa3 = &w3.x;

    float4 bv = *reinterpret_cast<const float4*>(cb + c0);
    float acc0 = bv.x, acc1 = bv.y, acc2 = bv.z, acc3 = bv.w;

    #pragma unroll
    for (int k = 0; k < 4; ++k) {
        int lk = l - 3 + k;
        if (lk < 0) continue;
        float4 v = *reinterpret_cast<const float4*>(zx + (size_t)(row-3+k)*DPROJ + DI + c0);
        acc0 += v.x * wa0[k];
        acc1 += v.y * wa1[k];
        acc2 += v.z * wa2[k];
        acc3 += v.w * wa3[k];
    }
    float4 o;
    o.x = acc0 / (1.f + expf(-acc0));
    o.y = acc1 / (1.f + expf(-acc1));
    o.z = acc2 / (1.f + expf(-acc2));
    o.w = acc3 / (1.f + expf(-acc3));
    *reinterpret_cast<float4*>(convo + (size_t)row*CONVD + c0) = o;

    if (threadIdx.x < NH) {
        int h = threadIdx.x;
        float v = zx[(size_t)row*DPROJ + DI + CONVD + h] + dt_bias[h];
        float dt = (v > 20.f) ? v : log1pf(expf(v));
        float A  = -expf(A_log[h]);
        dtb[row*NH + h] = dt;
        dAb[row*NH + h] = expf(dt * A);
    }
}

// ---------------- Kernel 3: sequential scan ----------------
// 256 blocks: (b, h, ps) with ps = p-octet. 256 threads: p_local=tid>>5 (8 rows),
// n0=(tid&31)*4 (4 states). Register-resident h, depth-2 prefetch, shfl reduce.
__global__ __launch_bounds__(256) void k_scan(const float* __restrict__ convo,
                                              const float* __restrict__ dtb,
                                              const float* __restrict__ dAb,
                                              const float* __restrict__ Dp,
                                              float* __restrict__ ybuf) {
    int blk = blockIdx.x;            // b*128 + h*8 + ps
    int ps  = blk & 7;
    int h   = (blk >> 3) & (NH-1);
    int b   = blk >> 7;
    int tid = threadIdx.x;
    int p_local = tid >> 5;
    int n0 = (tid & 31) * 4;
    int p  = ps*8 + p_local;

    float Dv = Dp[h];
    const float* base = convo + (size_t)b*SEQ*CONVD;
    const float* dtp  = dtb + (size_t)b*SEQ*NH + h;
    const float* dAp  = dAb + (size_t)b*SEQ*NH + h;

    float h0=0.f, h1=0.f, h2=0.f, h3=0.f;

    float dt0, dA0, xs0; float4 B0, C0;
    float dt1, dA1, xs1; float4 B1, C1;

    auto LD = [&](int l, float& dt, float& dA, float& xs, float4& Bv, float4& Cv) {
        const float* r = base + (size_t)l*CONVD;
        xs = r[h*HD + p];
        Bv = *reinterpret_cast<const float4*>(r + DI + n0);
        Cv = *reinterpret_cast<const float4*>(r + DI + DS + n0);
        dt = dtp[l*NH];
        dA = dAp[l*NH];
    };

    LD(0, dt0,dA0,xs0,B0,C0);
    LD(1, dt1,dA1,xs1,B1,C1);

    float* yout = ybuf + (size_t)b*SEQ*DI + h*HD + p;

    for (int l = 0; l < SEQ; ++l) {
        float dt=dt0, dA=dA0, xs=xs0; float4 Bv=B0, Cv=C0;
        dt0=dt1; dA0=dA1; xs0=xs1; B0=B1; C0=C1;
        if (l+2 < SEQ) LD(l+2, dt1,dA1,xs1,B1,C1);

        float dx = dt * xs;
        h0 = h0*dA + dx*Bv.x;
        h1 = h1*dA + dx*Bv.y;
        h2 = h2*dA + dx*Bv.z;
        h3 = h3*dA + dx*Bv.w;
        float part = h0*Cv.x + h1*Cv.y + h2*Cv.z + h3*Cv.w;
        part += __shfl_xor(part, 1);
        part += __shfl_xor(part, 2);
        part += __shfl_xor(part, 4);
        part += __shfl_xor(part, 8);
        part += __shfl_xor(part, 16);
        if ((tid & 31) == 0)
            yout[(size_t)l*DI] = part + xs*Dv;
    }
}

// ---------------- Kernel 4: gate + RMSNorm ----------------
__global__ __launch_bounds__(256) void k_gate(const float* __restrict__ zx,
                                              const float* __restrict__ ybuf,
                                              const float* __restrict__ nw,
                                              float* __restrict__ g) {
    int row = blockIdx.x;
    int t = threadIdx.x;
    const float* zr = zx + (size_t)row*DPROJ;
    const float* yr = ybuf + (size_t)row*DI;

    float4 zv = *reinterpret_cast<const float4*>(zr + t*4);
    float4 yv = *reinterpret_cast<const float4*>(yr + t*4);
    const float* za = &zv.x; const float* ya = &yv.x;
    float gv[4];
    float ss = 0.f;
    #pragma unroll
    for (int j = 0; j < 4; ++j) {
        float z = za[j], y = ya[j];
        float sz = z / (1.f + expf(-z));
        float gg = y * sz;
        gv[j] = gg;
        ss += gg*gg;
    }
    ss += __shfl_xor(ss, 1);
    ss += __shfl_xor(ss, 2);
    ss += __shfl_xor(ss, 4);
    ss += __shfl_xor(ss, 8);
    ss += __shfl_xor(ss, 16);
    ss += __shfl_xor(ss, 32);
    __shared__ float ls[4];
    if ((t & 63) == 0) ls[t >> 6] = ss;
    __syncthreads();
    float tot = ls[0] + ls[1] + ls[2] + ls[3];
    float scale = rsqrtf(tot * (1.f/DI) + 1e-5f);

    float4 nv = *reinterpret_cast<const float4*>(nw + t*4);
    const float* na = &nv.x;
    float4 og;
    og.x = gv[0]*scale*na[0];
    og.y = gv[1]*scale*na[1];
    og.z = gv[2]*scale*na[2];
    og.w = gv[3]*scale*na[3];
    *reinterpret_cast<float4*>(g + (size_t)row*DI + t*4) = og;
}

// ---------------- Kernel 5: out_proj GEMM ----------------
// out[m][d] = sum_e g[m][e] * Wo[d][e],  d in [0,512), K=1024
__global__ __launch_bounds__(64) void k_out_proj(const float* __restrict__ g,
                                                 const float* __restrict__ Wo,
                                                 float* __restrict__ out) {
    int d  = blockIdx.x * 64 + threadIdx.x;
    int m0 = blockIdx.y * 8;
    const float4* wr = reinterpret_cast<const float4*>(Wo + (size_t)d * DI);
    float acc[8] = {0.f,0.f,0.f,0.f,0.f,0.f,0.f,0.f};
    for (int k = 0; k < DI/4; ++k) {
        float4 w = wr[k];
        #pragma unroll
        for (int i = 0; i < 8; ++i) {
            float4 gv = *reinterpret_cast<const float4*>(g + (size_t)(m0+i)*DI + k*4);
            acc[i] += gv.x*w.x + gv.y*w.y + gv.z*w.z + gv.w*w.w;
        }
    }
    #pragma unroll
    for (int i = 0; i < 8; ++i)
        out[(size_t)(m0+i)*DM + d] = acc[i];
}

extern "C" void kernel_launch(void* const* d_in, const int* in_sizes, int n_in,
                              void* d_out, int out_size, void* d_ws, size_t ws_size,
                              hipStream_t stream) {
    const float* x         = (const float*)d_in[0];
    const float* in_proj_w = (const float*)d_in[1];
    const float* conv_w    = (const float*)d_in[2];
    const float* conv_b    = (const float*)d_in[3];
    const float* dt_bias   = (const float*)d_in[4];
    const float* A_log     = (const float*)d_in[5];
    const float* Dp        = (const float*)d_in[6];
    const float* norm_w    = (const float*)d_in[7];
    const float* out_proj_w= (const float*)d_in[8];
    float* out = (float*)d_out;

    float* ws    = (float*)d_ws;
    float* zx    = ws;                                   // 2048*2320
    float* convo = zx    + (size_t)ROWS*DPROJ;           // 2048*1280
    float* dtb   = convo + (size_t)ROWS*CONVD;           // 2048*16
    float* dAb   = dtb   + (size_t)ROWS*NH;              // 2048*16
    float* ybuf  = dAb   + (size_t)ROWS*NH;              // 2048*1024
    float* gbuf  = ybuf  + (size_t)ROWS*DI;              // 2048*1024

    k_in_proj <<<dim3((DPROJ+63)/64, ROWS/8), 64, 0, stream>>>(x, in_proj_w, zx);
    k_conv    <<<ROWS, CONVD/4, 0, stream>>>(zx, conv_w, conv_b, dt_bias, A_log,
                                             convo, dtb, dAb);
    k_scan    <<<BATCH*NH*8, 256, 0, stream>>>(convo, dtb, dAb, Dp, ybuf);
    k_gate    <<<ROWS, 256, 0, stream>>>(zx, ybuf, norm_w, gbuf);
    k_out_proj<<<dim3(DM/64, ROWS/8), 64, 0, stream>>>(gbuf, out_proj_w, out);
}

// Round 2
// 402.847 us; speedup vs baseline: 2.0937x; 2.0937x over previous
//
#include <hip/hip_runtime.h>
#include <math.h>

#define BATCH 2
#define SEQ 1024
#define DM 512
#define DI 1024
#define DS 128
#define NH 16
#define HD 64
#define CONVD 1280
#define DPROJ 2320
#define ROWS (BATCH*SEQ)   // 2048
#define NCH 16             // chunks per sequence
#define CHK 64             // chunk length

// ---------------- Kernel 1: in_proj GEMM ----------------
__global__ __launch_bounds__(64) void k_in_proj(const float* __restrict__ x,
                                                const float* __restrict__ W,
                                                float* __restrict__ out) {
    int e  = blockIdx.x * 64 + threadIdx.x;
    int m0 = blockIdx.y * 8;
    if (e >= DPROJ) return;
    const float4* wr = reinterpret_cast<const float4*>(W + (size_t)e * DM);
    float acc[8] = {0.f,0.f,0.f,0.f,0.f,0.f,0.f,0.f};
    for (int k = 0; k < DM/4; ++k) {
        float4 w = wr[k];
        #pragma unroll
        for (int i = 0; i < 8; ++i) {
            float4 xv = *reinterpret_cast<const float4*>(x + (size_t)(m0+i)*DM + k*4);
            acc[i] += xv.x*w.x + xv.y*w.y + xv.z*w.z + xv.w*w.w;
        }
    }
    #pragma unroll
    for (int i = 0; i < 8; ++i)
        out[(size_t)(m0+i)*DPROJ + e] = acc[i];
}

// ---------------- Kernel 2: depthwise conv + SiLU, plus dt / a=dt*A ----------------
__global__ __launch_bounds__(320) void k_conv(const float* __restrict__ zx,
                                              const float* __restrict__ cw,
                                              const float* __restrict__ cb,
                                              const float* __restrict__ dt_bias,
                                              const float* __restrict__ A_log,
                                              float* __restrict__ convo,
                                              float* __restrict__ dtb,
                                              float* __restrict__ abuf) {
    int row = blockIdx.x;            // b*SEQ + l
    int l   = row & (SEQ-1);
    int c0  = threadIdx.x * 4;

    const float4* cw4 = reinterpret_cast<const float4*>(cw);
    float4 w0 = cw4[c0+0], w1 = cw4[c0+1], w2 = cw4[c0+2], w3 = cw4[c0+3];
    const float* wa0 = &w0.x; const float* wa1 = &w1.x;
    const float* wa2 = &w2.x; const float* wa3 = &w3.x;

    float4 bv = *reinterpret_cast<const float4*>(cb + c0);
    float acc0 = bv.x, acc1 = bv.y, acc2 = bv.z, acc3 = bv.w;

    #pragma unroll
    for (int k = 0; k < 4; ++k) {
        int lk = l - 3 + k;
        if (lk < 0) continue;
        float4 v = *reinterpret_cast<const float4*>(zx + (size_t)(row-3+k)*DPROJ + DI + c0);
        acc0 += v.x * wa0[k];
        acc1 += v.y * wa1[k];
        acc2 += v.z * wa2[k];
        acc3 += v.w * wa3[k];
    }
    float4 o;
    o.x = acc0 / (1.f + expf(-acc0));
    o.y = acc1 / (1.f + expf(-acc1));
    o.z = acc2 / (1.f + expf(-acc2));
    o.w = acc3 / (1.f + expf(-acc3));
    *reinterpret_cast<float4*>(convo + (size_t)row*CONVD + c0) = o;

    if (threadIdx.x < NH) {
        int h = threadIdx.x;
        float v = zx[(size_t)row*DPROJ + DI + CONVD + h] + dt_bias[h];
        float dt = (v > 20.f) ? v : log1pf(expf(v));
        float A  = -expf(A_log[h]);
        dtb[row*NH + h] = dt;
        abuf[row*NH + h] = dt * A;     // log of decay
    }
}

// ---------------- Kernel 3a: per-chunk state contribution ----------------
// S[p][n] = sum_t dt_t*xs[t,p]*B[t,n]*exp(cum_end - cum_t);  P = exp(cum_end)
__global__ __launch_bounds__(256) void k_chunk_state(
    const float* __restrict__ convo, const float* __restrict__ dtb,
    const float* __restrict__ abuf, float* __restrict__ Sbuf,
    float* __restrict__ Pbuf) {
    int blk = blockIdx.x;                 // c + NCH*(h + NH*b)
    int c  = blk & (NCH-1);
    int bh = blk >> 4;
    int h  = bh & (NH-1);
    int row0 = (bh >> 4) * SEQ + c*CHK;
    int tid = threadIdx.x;

    __shared__ float s_B[CHK][132];
    __shared__ float s_xs[CHK][68];
    __shared__ float s_coef[CHK];

    {   // stage B row-major and xs row-major
        int t = tid >> 2, q = tid & 3;
        const float* r = convo + (size_t)(row0 + t)*CONVD;
        #pragma unroll
        for (int j = 0; j < 8; ++j) {
            float4 v = *reinterpret_cast<const float4*>(r + DI + q*32 + j*4);
            *reinterpret_cast<float4*>(&s_B[t][q*32 + j*4]) = v;
        }
        #pragma unroll
        for (int j = 0; j < 4; ++j) {
            float4 v = *reinterpret_cast<const float4*>(r + h*HD + q*16 + j*4);
            *reinterpret_cast<float4*>(&s_xs[t][q*16 + j*4]) = v;
        }
    }
    if (tid < CHK) {   // wave 0: prefix sum of a, coefficients
        float v = abuf[(size_t)(row0 + tid)*NH + h];
        #pragma unroll
        for (int off = 1; off < 64; off <<= 1) {
            float o = __shfl_up(v, off);
            if (tid >= off) v += o;
        }
        float vend = __shfl(v, 63);
        float dt = dtb[(size_t)(row0 + tid)*NH + h];
        s_coef[tid] = dt * expf(vend - v);
        if (tid == 63) Pbuf[blk] = expf(vend);
    }
    __syncthreads();

    int p0 = (tid & 15) * 4;
    int n0 = (tid >> 4) * 8;
    float acc[32];
    #pragma unroll
    for (int i = 0; i < 32; ++i) acc[i] = 0.f;

    for (int t = 0; t < CHK; ++t) {
        float coef = s_coef[t];
        float4 xv = *reinterpret_cast<const float4*>(&s_xs[t][p0]);
        float4 b0 = *reinterpret_cast<const float4*>(&s_B[t][n0]);
        float4 b1 = *reinterpret_cast<const float4*>(&s_B[t][n0+4]);
        float d[4] = {coef*xv.x, coef*xv.y, coef*xv.z, coef*xv.w};
        const float* ba = &b0.x;
        const float* bb = &b1.x;
        #pragma unroll
        for (int i = 0; i < 4; ++i) {
            #pragma unroll
            for (int j = 0; j < 4; ++j) {
                acc[i*8+j]   += d[i]*ba[j];
                acc[i*8+4+j] += d[i]*bb[j];
            }
        }
    }
    size_t base = (size_t)blk*(HD*DS);
    #pragma unroll
    for (int i = 0; i < 4; ++i) {
        #pragma unroll
        for (int j = 0; j < 8; j += 4) {
            float4 v = {acc[i*8+j], acc[i*8+j+1], acc[i*8+j+2], acc[i*8+j+3]};
            *reinterpret_cast<float4*>(Sbuf + base + (size_t)(p0+i)*DS + n0 + j) = v;
        }
    }
}

// ---------------- Kernel 3b: sequential pass over chunks (in place S -> h_in) ----------------
__global__ __launch_bounds__(256) void k_state_pass(float* __restrict__ Sbuf,
                                                    const float* __restrict__ Pbuf) {
    int bh = blockIdx.x;          // h + NH*b
    int off = threadIdx.x * 32;
    float hr[32];
    #pragma unroll
    for (int j = 0; j < 32; ++j) hr[j] = 0.f;

    for (int c = 0; c < NCH; ++c) {
        size_t base = ((size_t)(bh*NCH + c))*(HD*DS) + off;
        float P = Pbuf[bh*NCH + c];
        float s[32];
        #pragma unroll
        for (int j = 0; j < 8; ++j) {
            float4 v = *reinterpret_cast<const float4*>(Sbuf + base + j*4);
            s[j*4]=v.x; s[j*4+1]=v.y; s[j*4+2]=v.z; s[j*4+3]=v.w;
        }
        #pragma unroll
        for (int j = 0; j < 8; ++j) {
            float4 v = {hr[j*4],hr[j*4+1],hr[j*4+2],hr[j*4+3]};
            *reinterpret_cast<float4*>(Sbuf + base + j*4) = v;   // h_in for chunk c
        }
        #pragma unroll
        for (int j = 0; j < 32; ++j) hr[j] = hr[j]*P + s[j];
    }
}

// ---------------- Kernel 3c: per-chunk output ----------------
// Y[t,p] = sum_{s<=t} (C_t·B_s) e^{cum_t-cum_s} dt_s xs[s,p]  +  e^{cum_t} (C_t · h_in[p,:])  + D*xs[t,p]
__global__ __launch_bounds__(256) void k_chunk_out(
    const float* __restrict__ convo, const float* __restrict__ dtb,
    const float* __restrict__ abuf, const float* __restrict__ hin,
    const float* __restrict__ Dp, float* __restrict__ ybuf) {
    int blk = blockIdx.x;
    int c  = blk & (NCH-1);
    int bh = blk >> 4;
    int h  = bh & (NH-1);
    int row0 = (bh >> 4) * SEQ + c*CHK;
    int tid = threadIdx.x;

    __shared__ float s_U[CHK][68];   // k-major operand (cols = t)
    __shared__ float s_V[CHK][68];   // k-major operand (cols = s or p)
    __shared__ float s_M[CHK][68];   // M^T : [s][t]
    __shared__ float s_dx[CHK][68];  // dx[s][p]
    __shared__ float s_cum[CHK];

    if (tid < CHK) {   // prefix sum of a
        float v = abuf[(size_t)(row0 + tid)*NH + h];
        #pragma unroll
        for (int off = 1; off < 64; off <<= 1) {
            float o = __shfl_up(v, off);
            if (tid >= off) v += o;
        }
        s_cum[tid] = v;
    }
    {   // stage dx[s][p] = dt_s * xs[s,p]
        int s = tid >> 2, q = tid & 3;
        const float* r = convo + (size_t)(row0 + s)*CONVD;
        float dt = dtb[(size_t)(row0 + s)*NH + h];
        #pragma unroll
        for (int j = 0; j < 4; ++j) {
            float4 v = *reinterpret_cast<const float4*>(r + h*HD + q*16 + j*4);
            v.x*=dt; v.y*=dt; v.z*=dt; v.w*=dt;
            *reinterpret_cast<float4*>(&s_dx[s][q*16 + j*4]) = v;
        }
    }
    __syncthreads();

    int t0 = (tid & 15) * 4;
    int c0 = (tid >> 4) * 4;

    // ---- phase B: M[t][s] = C_t·B_s over K=128 (two k-halves) ----
    float m[16];
    #pragma unroll
    for (int i = 0; i < 16; ++i) m[i] = 0.f;

    for (int half = 0; half < 2; ++half) {
        {
            int r = tid >> 2, q = tid & 3;
            const float* rr = convo + (size_t)(row0 + r)*CONVD;
            #pragma unroll
            for (int j = 0; j < 4; ++j) {
                int k = q*16 + j*4;
                float4 cv = *reinterpret_cast<const float4*>(rr + DI + DS + half*64 + k);
                float4 bv = *reinterpret_cast<const float4*>(rr + DI + half*64 + k);
                s_U[k+0][r]=cv.x; s_U[k+1][r]=cv.y; s_U[k+2][r]=cv.z; s_U[k+3][r]=cv.w;
                s_V[k+0][r]=bv.x; s_V[k+1][r]=bv.y; s_V[k+2][r]=bv.z; s_V[k+3][r]=bv.w;
            }
        }
        __syncthreads();
        for (int k = 0; k < 64; ++k) {
            float4 cv = *reinterpret_cast<const float4*>(&s_U[k][t0]);
            float4 bv = *reinterpret_cast<const float4*>(&s_V[k][c0]);
            const float* ca = &cv.x; const float* ba = &bv.x;
            #pragma unroll
            for (int i = 0; i < 4; ++i)
                #pragma unroll
                for (int j = 0; j < 4; ++j)
                    m[i*4+j] += ca[i]*ba[j];
        }
        __syncthreads();
    }
    {   // decay + causal mask, write M^T
        #pragma unroll
        for (int i = 0; i < 4; ++i) {
            float cumt = s_cum[t0+i];
            #pragma unroll
            for (int j = 0; j < 4; ++j) {
                int s = c0 + j;
                float v = (s <= t0+i) ? m[i*4+j]*expf(cumt - s_cum[s]) : 0.f;
                s_M[s][t0+i] = v;
            }
        }
    }
    __syncthreads();

    // ---- phase C: Y_local[t][p] = sum_s M[t][s] dx[s][p] ----
    float acc[16];
    #pragma unroll
    for (int i = 0; i < 16; ++i) acc[i] = 0.f;
    for (int s = 0; s < CHK; ++s) {
        float4 mv = *reinterpret_cast<const float4*>(&s_M[s][t0]);
        float4 dv = *reinterpret_cast<const float4*>(&s_dx[s][c0]);
        const float* ma = &mv.x; const float* da = &dv.x;
        #pragma unroll
        for (int i = 0; i < 4; ++i)
            #pragma unroll
            for (int j = 0; j < 4; ++j)
                acc[i*4+j] += ma[i]*da[j];
    }

    // ---- phase D: cross term, C pre-scaled by e^{cum_t}, vs h_in (two k-halves) ----
    for (int half = 0; half < 2; ++half) {
        __syncthreads();
        {
            int r = tid >> 2, q = tid & 3;
            const float* rr = convo + (size_t)(row0 + r)*CONVD;
            float et = expf(s_cum[r]);
            const float* hr = hin + ((size_t)blk)*(HD*DS) + (size_t)r*DS + half*64;
            #pragma unroll
            for (int j = 0; j < 4; ++j) {
                int k = q*16 + j*4;
                float4 cv = *reinterpret_cast<const float4*>(rr + DI + DS + half*64 + k);
                s_U[k+0][r]=cv.x*et; s_U[k+1][r]=cv.y*et; s_U[k+2][r]=cv.z*et; s_U[k+3][r]=cv.w*et;
                float4 hv = *reinterpret_cast<const float4*>(hr + k);
                s_V[k+0][r]=hv.x; s_V[k+1][r]=hv.y; s_V[k+2][r]=hv.z; s_V[k+3][r]=hv.w;
            }
        }
        __syncthreads();
        for (int k = 0; k < 64; ++k) {
            float4 cv = *reinterpret_cast<const float4*>(&s_U[k][t0]);
            float4 hv = *reinterpret_cast<const float4*>(&s_V[k][c0]);
            const float* ca = &cv.x; const float* ha = &hv.x;
            #pragma unroll
            for (int i = 0; i < 4; ++i)
                #pragma unroll
                for (int j = 0; j < 4; ++j)
                    acc[i*4+j] += ca[i]*ha[j];
        }
    }

    // ---- epilogue: + D*xs, write Y ----
    float Dv = Dp[h];
    #pragma unroll
    for (int i = 0; i < 4; ++i) {
        int t = t0 + i;
        const float* rr = convo + (size_t)(row0 + t)*CONVD;
        float4 xv = *reinterpret_cast<const float4*>(rr + h*HD + c0);
        float4 o;
        o.x = acc[i*4+0] + Dv*xv.x;
        o.y = acc[i*4+1] + Dv*xv.y;
        o.z = acc[i*4+2] + Dv*xv.z;
        o.w = acc[i*4+3] + Dv*xv.w;
        *reinterpret_cast<float4*>(ybuf + (size_t)(row0+t)*DI + h*HD + c0) = o;
    }
}

// ---------------- Kernel 4: gate + RMSNorm ----------------
__global__ __launch_bounds__(256) void k_gate(const float* __restrict__ zx,
                                              const float* __restrict__ ybuf,
                                              const float* __restrict__ nw,
                                              float* __restrict__ g) {
    int row = blockIdx.x;
    int t = threadIdx.x;
    const float* zr = zx + (size_t)row*DPROJ;
    const float* yr = ybuf + (size_t)row*DI;

    float4 zv = *reinterpret_cast<const float4*>(zr + t*4);
    float4 yv = *reinterpret_cast<const float4*>(yr + t*4);
    const float* za = &zv.x; const float* ya = &yv.x;
    float gv[4];
    float ss = 0.f;
    #pragma unroll
    for (int j = 0; j < 4; ++j) {
        float z = za[j], y = ya[j];
        float sz = z / (1.f + expf(-z));
        float gg = y * sz;
        gv[j] = gg;
        ss += gg*gg;
    }
    ss += __shfl_xor(ss, 1);
    ss += __shfl_xor(ss, 2);
    ss += __shfl_xor(ss, 4);
    ss += __shfl_xor(ss, 8);
    ss += __shfl_xor(ss, 16);
    ss += __shfl_xor(ss, 32);
    __shared__ float ls[4];
    if ((t & 63) == 0) ls[t >> 6] = ss;
    __syncthreads();
    float tot = ls[0] + ls[1] + ls[2] + ls[3];
    float scale = rsqrtf(tot * (1.f/DI) + 1e-5f);

    float4 nv = *reinterpret_cast<const float4*>(nw + t*4);
    const float* na = &nv.x;
    float4 og;
    og.x = gv[0]*scale*na[0];
    og.y = gv[1]*scale*na[1];
    og.z = gv[2]*scale*na[2];
    og.w = gv[3]*scale*na[3];
    *reinterpret_cast<float4*>(g + (size_t)row*DI + t*4) = og;
}

// ---------------- Kernel 5: out_proj GEMM ----------------
__global__ __launch_bounds__(64) void k_out_proj(const float* __restrict__ g,
                                                 const float* __restrict__ Wo,
                                                 float* __restrict__ out) {
    int d  = blockIdx.x * 64 + threadIdx.x;
    int m0 = blockIdx.y * 8;
    const float4* wr = reinterpret_cast<const float4*>(Wo + (size_t)d * DI);
    float acc[8] = {0.f,0.f,0.f,0.f,0.f,0.f,0.f,0.f};
    for (int k = 0; k < DI/4; ++k) {
        float4 w = wr[k];
        #pragma unroll
        for (int i = 0; i < 8; ++i) {
            float4 gv = *reinterpret_cast<const float4*>(g + (size_t)(m0+i)*DI + k*4);
            acc[i] += gv.x*w.x + gv.y*w.y + gv.z*w.z + gv.w*w.w;
        }
    }
    #pragma unroll
    for (int i = 0; i < 8; ++i)
        out[(size_t)(m0+i)*DM + d] = acc[i];
}

extern "C" void kernel_launch(void* const* d_in, const int* in_sizes, int n_in,
                              void* d_out, int out_size, void* d_ws, size_t ws_size,
                              hipStream_t stream) {
    const float* x         = (const float*)d_in[0];
    const float* in_proj_w = (const float*)d_in[1];
    const float* conv_w    = (const float*)d_in[2];
    const float* conv_b    = (const float*)d_in[3];
    const float* dt_bias   = (const float*)d_in[4];
    const float* A_log     = (const float*)d_in[5];
    const float* Dp        = (const float*)d_in[6];
    const float* norm_w    = (const float*)d_in[7];
    const float* out_proj_w= (const float*)d_in[8];
    float* out = (float*)d_out;

    float* ws    = (float*)d_ws;
    float* zx    = ws;                                    // 2048*2320
    float* convo = zx    + (size_t)ROWS*DPROJ;            // 2048*1280
    float* dtb   = convo + (size_t)ROWS*CONVD;            // 2048*16
    float* abuf  = dtb   + (size_t)ROWS*NH;               // 2048*16
    float* ybuf  = abuf  + (size_t)ROWS*NH;               // 2048*1024
    float* Sbuf  = ybuf  + (size_t)ROWS*DI;               // 512*8192 (S -> h_in)
    float* Pbuf  = Sbuf  + (size_t)BATCH*NH*NCH*HD*DS;    // 512
    float* gbuf  = convo;                                 // reuse convo (done after k_chunk_out)

    k_in_proj <<<dim3((DPROJ+63)/64, ROWS/8), 64, 0, stream>>>(x, in_proj_w, zx);
    k_conv    <<<ROWS, CONVD/4, 0, stream>>>(zx, conv_w, conv_b, dt_bias, A_log,
                                             convo, dtb, abuf);
    k_chunk_state<<<BATCH*NH*NCH, 256, 0, stream>>>(convo, dtb, abuf, Sbuf, Pbuf);
    k_state_pass <<<BATCH*NH, 256, 0, stream>>>(Sbuf, Pbuf);
    k_chunk_out  <<<BATCH*NH*NCH, 256, 0, stream>>>(convo, dtb, abuf, Sbuf, Dp, ybuf);
    k_gate    <<<ROWS, 256, 0, stream>>>(zx, ybuf, norm_w, gbuf);
    k_out_proj<<<dim3(DM/64, ROWS/8), 64, 0, stream>>>(gbuf, out_proj_w, out);
}

// Round 3
// 125.821 us; speedup vs baseline: 6.7036x; 3.2017x over previous
//
#include <hip/hip_runtime.h>
#include <math.h>

#define BATCH 2
#define SEQ 1024
#define DM 512
#define DI 1024
#define DS 128
#define NH 16
#define HD 64
#define CONVD 1280
#define DPROJ 2320
#define ROWS (BATCH*SEQ)   // 2048
#define NCH 16             // chunks per sequence
#define CHK 64             // chunk length
#define NPAD 2432          // in_proj N padded to 19*128

typedef unsigned short u16;
typedef unsigned int   u32;
typedef u16   u16x4 __attribute__((ext_vector_type(4)));
typedef u16   u16x8 __attribute__((ext_vector_type(8)));
typedef short bf16x8 __attribute__((ext_vector_type(8)));
typedef float f32x4 __attribute__((ext_vector_type(4)));

__device__ __forceinline__ u16 f2bf(float f) {
    u32 u = __float_as_uint(f);
    return (u16)((u + 0x7fffu + ((u >> 16) & 1u)) >> 16);
}
__device__ __forceinline__ float bf2f(u16 h) {
    return __uint_as_float(((u32)h) << 16);
}
__device__ __forceinline__ void gl_lds16(const u16* g, u16* lds) {
    __builtin_amdgcn_global_load_lds((const __attribute__((address_space(1))) void*)g,
                                     (__attribute__((address_space(3))) void*)lds,
                                     16, 0, 0);
}

// ---------------- fp32 -> bf16 conversion (with zero pad to n_total) ----------------
__global__ __launch_bounds__(256) void k_cvt(const float* __restrict__ src,
                                             u16* __restrict__ dst,
                                             int n_src, int n_total) {
    int idx = (blockIdx.x * 256 + threadIdx.x) * 8;
    if (idx >= n_total) return;
    u16x8 o;
    if (idx + 8 <= n_src) {
        float4 a = *reinterpret_cast<const float4*>(src + idx);
        float4 b = *reinterpret_cast<const float4*>(src + idx + 4);
        o[0]=f2bf(a.x); o[1]=f2bf(a.y); o[2]=f2bf(a.z); o[3]=f2bf(a.w);
        o[4]=f2bf(b.x); o[5]=f2bf(b.y); o[6]=f2bf(b.z); o[7]=f2bf(b.w);
    } else {
        #pragma unroll
        for (int e = 0; e < 8; ++e)
            o[e] = (idx + e < n_src) ? f2bf(src[idx + e]) : (u16)0;
    }
    *reinterpret_cast<u16x8*>(dst + idx) = o;
}

// ---------------- MFMA GEMM: C[m][n] = sum_k A[m][k]*B[n][k]  (both K-major bf16) ----------------
// 256 threads, 4 waves in 2x2; BK=32; sigma-swizzled LDS chunks (q' = q ^ ((row>>1)&3)).
template<int BM, int BN, int K>
__global__ __launch_bounds__(256) void k_gemm(const u16* __restrict__ A,
                                              const u16* __restrict__ B,
                                              float* __restrict__ C,
                                              int ldc, int ncols) {
    constexpr int WTM = BM/2, WTN = BN/2, FM = WTM/16, FN = WTN/16;
    constexpr int CA = BM*4/256, CB = BN*4/256;
    __shared__ u16 As[BM*32];
    __shared__ u16 Bs[BN*32];
    int tid  = threadIdx.x;
    int lane = tid & 63, wave = tid >> 6;
    int wr = wave >> 1, wc = wave & 1;
    size_t bm = (size_t)blockIdx.y * BM, bn = (size_t)blockIdx.x * BN;

    const u16* srcA[CA]; u16* dstA[CA];
    #pragma unroll
    for (int j = 0; j < CA; ++j) {
        int i = j*256 + tid;
        int row = i >> 2, q = (i & 3) ^ ((row >> 1) & 3);
        srcA[j] = A + (bm + row) * (size_t)K + q*8;
        dstA[j] = As + i*8;
    }
    const u16* srcB[CB]; u16* dstB[CB];
    #pragma unroll
    for (int j = 0; j < CB; ++j) {
        int i = j*256 + tid;
        int row = i >> 2, q = (i & 3) ^ ((row >> 1) & 3);
        srcB[j] = B + (bn + row) * (size_t)K + q*8;
        dstB[j] = Bs + i*8;
    }

    int kq = lane >> 4;
    int aoff[FM], boff[FN];
    #pragma unroll
    for (int fi = 0; fi < FM; ++fi) {
        int row = wr*WTM + fi*16 + (lane & 15);
        aoff[fi] = (row*4 + (kq ^ ((row >> 1) & 3))) * 8;
    }
    #pragma unroll
    for (int fj = 0; fj < FN; ++fj) {
        int row = wc*WTN + fj*16 + (lane & 15);
        boff[fj] = (row*4 + (kq ^ ((row >> 1) & 3))) * 8;
    }

    f32x4 acc[FM][FN];
    #pragma unroll
    for (int fi = 0; fi < FM; ++fi)
        #pragma unroll
        for (int fj = 0; fj < FN; ++fj)
            acc[fi][fj] = (f32x4){0.f, 0.f, 0.f, 0.f};

    for (int k0 = 0; k0 < K; k0 += 32) {
        __syncthreads();
        #pragma unroll
        for (int j = 0; j < CA; ++j) gl_lds16(srcA[j] + k0, dstA[j]);
        #pragma unroll
        for (int j = 0; j < CB; ++j) gl_lds16(srcB[j] + k0, dstB[j]);
        __syncthreads();
        bf16x8 av[FM], bv[FN];
        #pragma unroll
        for (int fi = 0; fi < FM; ++fi)
            av[fi] = *reinterpret_cast<const bf16x8*>(As + aoff[fi]);
        #pragma unroll
        for (int fj = 0; fj < FN; ++fj)
            bv[fj] = *reinterpret_cast<const bf16x8*>(Bs + boff[fj]);
        #pragma unroll
        for (int fi = 0; fi < FM; ++fi)
            #pragma unroll
            for (int fj = 0; fj < FN; ++fj)
                acc[fi][fj] = __builtin_amdgcn_mfma_f32_16x16x32_bf16(
                    av[fi], bv[fj], acc[fi][fj], 0, 0, 0);
    }

    #pragma unroll
    for (int fi = 0; fi < FM; ++fi) {
        size_t grow0 = bm + wr*WTM + fi*16 + (lane >> 4)*4;
        #pragma unroll
        for (int fj = 0; fj < FN; ++fj) {
            size_t gcol = bn + wc*WTN + fj*16 + (lane & 15);
            if ((int)gcol < ncols) {
                #pragma unroll
                for (int r = 0; r < 4; ++r)
                    C[(grow0 + r)*ldc + gcol] = acc[fi][fj][r];
            }
        }
    }
}

// ---------------- dt in exact fp32: v = x . W_dt[h] + dt_bias ----------------
__global__ __launch_bounds__(256) void k_dt(const float* __restrict__ x,
                                            const float* __restrict__ W,
                                            const float* __restrict__ dt_bias,
                                            const float* __restrict__ A_log,
                                            float* __restrict__ dtb,
                                            float* __restrict__ abuf) {
    int wave = threadIdx.x >> 6, lane = threadIdx.x & 63;
    int row = blockIdx.x * 4 + wave;
    int h = lane & 15, part = lane >> 4;
    const float* xr = x + (size_t)row * DM + part*128;
    const float* wr = W + (size_t)(DI + CONVD + h) * DM + part*128;
    float acc = 0.f;
    #pragma unroll 4
    for (int j = 0; j < 32; ++j) {
        float4 xv = *reinterpret_cast<const float4*>(xr + j*4);
        float4 wv = *reinterpret_cast<const float4*>(wr + j*4);
        acc += xv.x*wv.x + xv.y*wv.y + xv.z*wv.z + xv.w*wv.w;
    }
    acc += __shfl_xor(acc, 16);
    acc += __shfl_xor(acc, 32);
    if (part == 0) {
        float v = acc + dt_bias[h];
        float dt = (v > 20.f) ? v : log1pf(expf(v));
        dtb[row*NH + h]  = dt;
        abuf[row*NH + h] = dt * (-expf(A_log[h]));
    }
}

// ---------------- depthwise conv + SiLU ----------------
__global__ __launch_bounds__(320) void k_conv(const float* __restrict__ zx,
                                              const float* __restrict__ cw,
                                              const float* __restrict__ cb,
                                              float* __restrict__ convo) {
    int row = blockIdx.x;            // b*SEQ + l
    int l   = row & (SEQ-1);
    int c0  = threadIdx.x * 4;

    const float4* cw4 = reinterpret_cast<const float4*>(cw);
    float4 w0 = cw4[c0+0], w1 = cw4[c0+1], w2 = cw4[c0+2], w3 = cw4[c0+3];
    const float* wa0 = &w0.x; const float* wa1 = &w1.x;
    const float* wa2 = &w2.x; const float* wa3 = &w3.x;

    float4 bv = *reinterpret_cast<const float4*>(cb + c0);
    float acc0 = bv.x, acc1 = bv.y, acc2 = bv.z, acc3 = bv.w;

    #pragma unroll
    for (int k = 0; k < 4; ++k) {
        int lk = l - 3 + k;
        if (lk < 0) continue;
        float4 v = *reinterpret_cast<const float4*>(zx + (size_t)(row-3+k)*DPROJ + DI + c0);
        acc0 += v.x * wa0[k];
        acc1 += v.y * wa1[k];
        acc2 += v.z * wa2[k];
        acc3 += v.w * wa3[k];
    }
    float4 o;
    o.x = acc0 / (1.f + expf(-acc0));
    o.y = acc1 / (1.f + expf(-acc1));
    o.z = acc2 / (1.f + expf(-acc2));
    o.w = acc3 / (1.f + expf(-acc3));
    *reinterpret_cast<float4*>(convo + (size_t)row*CONVD + c0) = o;
}

// ---------------- per-chunk state contribution (bf16 out) ----------------
__global__ __launch_bounds__(256) void k_chunk_state(
    const float* __restrict__ convo, const float* __restrict__ dtb,
    const float* __restrict__ abuf, u16* __restrict__ Sb,
    float* __restrict__ Pbuf) {
    int blk = blockIdx.x;                 // c + NCH*(h + NH*b)
    int c  = blk & (NCH-1);
    int bh = blk >> 4;
    int h  = bh & (NH-1);
    int row0 = (bh >> 4) * SEQ + c*CHK;
    int tid = threadIdx.x;

    __shared__ float s_B[CHK][132];
    __shared__ float s_xs[CHK][68];
    __shared__ float s_coef[CHK];

    {
        int t = tid >> 2, q = tid & 3;
        const float* r = convo + (size_t)(row0 + t)*CONVD;
        #pragma unroll
        for (int j = 0; j < 8; ++j) {
            float4 v = *reinterpret_cast<const float4*>(r + DI + q*32 + j*4);
            *reinterpret_cast<float4*>(&s_B[t][q*32 + j*4]) = v;
        }
        #pragma unroll
        for (int j = 0; j < 4; ++j) {
            float4 v = *reinterpret_cast<const float4*>(r + h*HD + q*16 + j*4);
            *reinterpret_cast<float4*>(&s_xs[t][q*16 + j*4]) = v;
        }
    }
    if (tid < CHK) {
        float v = abuf[(size_t)(row0 + tid)*NH + h];
        #pragma unroll
        for (int off = 1; off < 64; off <<= 1) {
            float o = __shfl_up(v, off);
            if (tid >= off) v += o;
        }
        float vend = __shfl(v, 63);
        float dt = dtb[(size_t)(row0 + tid)*NH + h];
        s_coef[tid] = dt * expf(vend - v);
        if (tid == 63) Pbuf[blk] = expf(vend);
    }
    __syncthreads();

    int p0 = (tid & 15) * 4;
    int n0 = (tid >> 4) * 8;
    float acc[32];
    #pragma unroll
    for (int i = 0; i < 32; ++i) acc[i] = 0.f;

    for (int t = 0; t < CHK; ++t) {
        float coef = s_coef[t];
        float4 xv = *reinterpret_cast<const float4*>(&s_xs[t][p0]);
        float4 b0 = *reinterpret_cast<const float4*>(&s_B[t][n0]);
        float4 b1 = *reinterpret_cast<const float4*>(&s_B[t][n0+4]);
        float d[4] = {coef*xv.x, coef*xv.y, coef*xv.z, coef*xv.w};
        const float* ba = &b0.x;
        const float* bb = &b1.x;
        #pragma unroll
        for (int i = 0; i < 4; ++i) {
            #pragma unroll
            for (int j = 0; j < 4; ++j) {
                acc[i*8+j]   += d[i]*ba[j];
                acc[i*8+4+j] += d[i]*bb[j];
            }
        }
    }
    u16* outp = Sb + (size_t)blk*(HD*DS);
    #pragma unroll
    for (int i = 0; i < 4; ++i) {
        #pragma unroll
        for (int jh = 0; jh < 2; ++jh) {
            u16x4 v = { f2bf(acc[i*8+jh*4]), f2bf(acc[i*8+jh*4+1]),
                        f2bf(acc[i*8+jh*4+2]), f2bf(acc[i*8+jh*4+3]) };
            *reinterpret_cast<u16x4*>(outp + (size_t)(p0+i)*DS + n0 + jh*4) = v;
        }
    }
}

// ---------------- sequential pass over chunks (bf16 in place S -> h_in) ----------------
__global__ __launch_bounds__(256) void k_state_pass(u16* __restrict__ Sb,
                                                    const float* __restrict__ Pbuf) {
    int bh = blockIdx.x;          // h + NH*b
    int off = threadIdx.x * 32;
    float hr[32];
    #pragma unroll
    for (int j = 0; j < 32; ++j) hr[j] = 0.f;

    for (int c = 0; c < NCH; ++c) {
        u16* base = Sb + ((size_t)(bh*NCH + c))*(HD*DS) + off;
        float P = Pbuf[bh*NCH + c];
        float s[32];
        #pragma unroll
        for (int j = 0; j < 4; ++j) {
            u16x8 v = *reinterpret_cast<const u16x8*>(base + j*8);
            #pragma unroll
            for (int e = 0; e < 8; ++e) s[j*8+e] = bf2f(v[e]);
        }
        #pragma unroll
        for (int j = 0; j < 4; ++j) {
            u16x8 w;
            #pragma unroll
            for (int e = 0; e < 8; ++e) w[e] = f2bf(hr[j*8+e]);
            *reinterpret_cast<u16x8*>(base + j*8) = w;
        }
        #pragma unroll
        for (int j = 0; j < 32; ++j) hr[j] = hr[j]*P + s[j];
    }
}

// ---------------- per-chunk output ----------------
__global__ __launch_bounds__(256) void k_chunk_out(
    const float* __restrict__ convo, const float* __restrict__ dtb,
    const float* __restrict__ abuf, const u16* __restrict__ hin,
    const float* __restrict__ Dp, float* __restrict__ ybuf) {
    int blk = blockIdx.x;
    int c  = blk & (NCH-1);
    int bh = blk >> 4;
    int h  = bh & (NH-1);
    int row0 = (bh >> 4) * SEQ + c*CHK;
    int tid = threadIdx.x;

    __shared__ float s_U[CHK][68];
    __shared__ float s_V[CHK][68];
    __shared__ float s_M[CHK][68];
    __shared__ float s_dx[CHK][68];
    __shared__ float s_cum[CHK];

    if (tid < CHK) {
        float v = abuf[(size_t)(row0 + tid)*NH + h];
        #pragma unroll
        for (int off = 1; off < 64; off <<= 1) {
            float o = __shfl_up(v, off);
            if (tid >= off) v += o;
        }
        s_cum[tid] = v;
    }
    {
        int s = tid >> 2, q = tid & 3;
        const float* r = convo + (size_t)(row0 + s)*CONVD;
        float dt = dtb[(size_t)(row0 + s)*NH + h];
        #pragma unroll
        for (int j = 0; j < 4; ++j) {
            float4 v = *reinterpret_cast<const float4*>(r + h*HD + q*16 + j*4);
            v.x*=dt; v.y*=dt; v.z*=dt; v.w*=dt;
            *reinterpret_cast<float4*>(&s_dx[s][q*16 + j*4]) = v;
        }
    }
    __syncthreads();

    int t0 = (tid & 15) * 4;
    int c0 = (tid >> 4) * 4;

    float m[16];
    #pragma unroll
    for (int i = 0; i < 16; ++i) m[i] = 0.f;

    for (int half = 0; half < 2; ++half) {
        {
            int r = tid >> 2, q = tid & 3;
            const float* rr = convo + (size_t)(row0 + r)*CONVD;
            #pragma unroll
            for (int j = 0; j < 4; ++j) {
                int k = q*16 + j*4;
                float4 cv = *reinterpret_cast<const float4*>(rr + DI + DS + half*64 + k);
                float4 bv = *reinterpret_cast<const float4*>(rr + DI + half*64 + k);
                s_U[k+0][r]=cv.x; s_U[k+1][r]=cv.y; s_U[k+2][r]=cv.z; s_U[k+3][r]=cv.w;
                s_V[k+0][r]=bv.x; s_V[k+1][r]=bv.y; s_V[k+2][r]=bv.z; s_V[k+3][r]=bv.w;
            }
        }
        __syncthreads();
        for (int k = 0; k < 64; ++k) {
            float4 cv = *reinterpret_cast<const float4*>(&s_U[k][t0]);
            float4 bv = *reinterpret_cast<const float4*>(&s_V[k][c0]);
            const float* ca = &cv.x; const float* ba = &bv.x;
            #pragma unroll
            for (int i = 0; i < 4; ++i)
                #pragma unroll
                for (int j = 0; j < 4; ++j)
                    m[i*4+j] += ca[i]*ba[j];
        }
        __syncthreads();
    }
    {
        #pragma unroll
        for (int i = 0; i < 4; ++i) {
            float cumt = s_cum[t0+i];
            #pragma unroll
            for (int j = 0; j < 4; ++j) {
                int s = c0 + j;
                float v = (s <= t0+i) ? m[i*4+j]*expf(cumt - s_cum[s]) : 0.f;
                s_M[s][t0+i] = v;
            }
        }
    }
    __syncthreads();

    float acc[16];
    #pragma unroll
    for (int i = 0; i < 16; ++i) acc[i] = 0.f;
    for (int s = 0; s < CHK; ++s) {
        float4 mv = *reinterpret_cast<const float4*>(&s_M[s][t0]);
        float4 dv = *reinterpret_cast<const float4*>(&s_dx[s][c0]);
        const float* ma = &mv.x; const float* da = &dv.x;
        #pragma unroll
        for (int i = 0; i < 4; ++i)
            #pragma unroll
            for (int j = 0; j < 4; ++j)
                acc[i*4+j] += ma[i]*da[j];
    }

    for (int half = 0; half < 2; ++half) {
        __syncthreads();
        {
            int r = tid >> 2, q = tid & 3;
            const float* rr = convo + (size_t)(row0 + r)*CONVD;
            float et = expf(s_cum[r]);
            const u16* hr = hin + ((size_t)blk)*(HD*DS) + (size_t)r*DS + half*64;
            #pragma unroll
            for (int j = 0; j < 4; ++j) {
                int k = q*16 + j*4;
                float4 cv = *reinterpret_cast<const float4*>(rr + DI + DS + half*64 + k);
                s_U[k+0][r]=cv.x*et; s_U[k+1][r]=cv.y*et; s_U[k+2][r]=cv.z*et; s_U[k+3][r]=cv.w*et;
                u16x4 hv = *reinterpret_cast<const u16x4*>(hr + k);
                s_V[k+0][r]=bf2f(hv[0]); s_V[k+1][r]=bf2f(hv[1]);
                s_V[k+2][r]=bf2f(hv[2]); s_V[k+3][r]=bf2f(hv[3]);
            }
        }
        __syncthreads();
        for (int k = 0; k < 64; ++k) {
            float4 cv = *reinterpret_cast<const float4*>(&s_U[k][t0]);
            float4 hv = *reinterpret_cast<const float4*>(&s_V[k][c0]);
            const float* ca = &cv.x; const float* ha = &hv.x;
            #pragma unroll
            for (int i = 0; i < 4; ++i)
                #pragma unroll
                for (int j = 0; j < 4; ++j)
                    acc[i*4+j] += ca[i]*ha[j];
        }
    }

    float Dv = Dp[h];
    #pragma unroll
    for (int i = 0; i < 4; ++i) {
        int t = t0 + i;
        const float* rr = convo + (size_t)(row0 + t)*CONVD;
        float4 xv = *reinterpret_cast<const float4*>(rr + h*HD + c0);
        float4 o;
        o.x = acc[i*4+0] + Dv*xv.x;
        o.y = acc[i*4+1] + Dv*xv.y;
        o.z = acc[i*4+2] + Dv*xv.z;
        o.w = acc[i*4+3] + Dv*xv.w;
        *reinterpret_cast<float4*>(ybuf + (size_t)(row0+t)*DI + h*HD + c0) = o;
    }
}

// ---------------- gate + RMSNorm (bf16 out) ----------------
__global__ __launch_bounds__(256) void k_gate(const float* __restrict__ zx,
                                              const float* __restrict__ ybuf,
                                              const float* __restrict__ nw,
                                              u16* __restrict__ g) {
    int row = blockIdx.x;
    int t = threadIdx.x;
    const float* zr = zx + (size_t)row*DPROJ;
    const float* yr = ybuf + (size_t)row*DI;

    float4 zv = *reinterpret_cast<const float4*>(zr + t*4);
    float4 yv = *reinterpret_cast<const float4*>(yr + t*4);
    const float* za = &zv.x; const float* ya = &yv.x;
    float gv[4];
    float ss = 0.f;
    #pragma unroll
    for (int j = 0; j < 4; ++j) {
        float z = za[j], y = ya[j];
        float sz = z / (1.f + expf(-z));
        float gg = y * sz;
        gv[j] = gg;
        ss += gg*gg;
    }
    ss += __shfl_xor(ss, 1);
    ss += __shfl_xor(ss, 2);
    ss += __shfl_xor(ss, 4);
    ss += __shfl_xor(ss, 8);
    ss += __shfl_xor(ss, 16);
    ss += __shfl_xor(ss, 32);
    __shared__ float ls[4];
    if ((t & 63) == 0) ls[t >> 6] = ss;
    __syncthreads();
    float tot = ls[0] + ls[1] + ls[2] + ls[3];
    float scale = rsqrtf(tot * (1.f/DI) + 1e-5f);

    float4 nv = *reinterpret_cast<const float4*>(nw + t*4);
    const float* na = &nv.x;
    u16x4 og = { f2bf(gv[0]*scale*na[0]), f2bf(gv[1]*scale*na[1]),
                 f2bf(gv[2]*scale*na[2]), f2bf(gv[3]*scale*na[3]) };
    *reinterpret_cast<u16x4*>(g + (size_t)row*DI + t*4) = og;
}

extern "C" void kernel_launch(void* const* d_in, const int* in_sizes, int n_in,
                              void* d_out, int out_size, void* d_ws, size_t ws_size,
                              hipStream_t stream) {
    const float* x         = (const float*)d_in[0];
    const float* in_proj_w = (const float*)d_in[1];
    const float* conv_w    = (const float*)d_in[2];
    const float* conv_b    = (const float*)d_in[3];
    const float* dt_bias   = (const float*)d_in[4];
    const float* A_log     = (const float*)d_in[5];
    const float* Dp        = (const float*)d_in[6];
    const float* norm_w    = (const float*)d_in[7];
    const float* out_proj_w= (const float*)d_in[8];
    float* out = (float*)d_out;

    float* ws    = (float*)d_ws;
    float* zx    = ws;                                   // 2048*2320
    float* convo = zx    + (size_t)ROWS*DPROJ;           // 2048*1280
    float* dtb   = convo + (size_t)ROWS*CONVD;           // 2048*16
    float* abuf  = dtb   + (size_t)ROWS*NH;              // 2048*16
    float* ybuf  = abuf  + (size_t)ROWS*NH;              // 2048*1024
    float* R     = ybuf  + (size_t)ROWS*DI;              // 2,097,152 floats (8MB) shared region
    float* Pbuf  = R     + 2097152;                      // 512
    float* WobF  = Pbuf  + 512;                          // 262,144 floats (Wob bf16)

    u16* xb  = (u16*)R;                                  // 2048*512   (in_proj phase)
    u16* Wb  = xb + (size_t)ROWS*DM;                     // 2432*512   (in_proj phase)
    u16* Sb  = (u16*)R;                                  // 512*8192   (scan phase, aliases xb/Wb)
    u16* gb  = (u16*)R;                                  // 2048*1024  (gate phase, aliases Sb)
    u16* Wob = (u16*)WobF;                               // 512*1024

    // bf16 conversions
    k_cvt<<<(ROWS*DM)/2048, 256, 0, stream>>>(x, xb, ROWS*DM, ROWS*DM);
    k_cvt<<<(NPAD*DM)/2048, 256, 0, stream>>>(in_proj_w, Wb, DPROJ*DM, NPAD*DM);
    k_cvt<<<(DM*DI)/2048,  256, 0, stream>>>(out_proj_w, Wob, DM*DI, DM*DI);

    // in_proj: M=2048 (BM=64), N=2432 padded (BN=128), K=512
    k_gemm<64,128,512><<<dim3(NPAD/128, ROWS/64), 256, 0, stream>>>(xb, Wb, zx, DPROJ, DPROJ);

    k_dt  <<<ROWS/4, 256, 0, stream>>>(x, in_proj_w, dt_bias, A_log, dtb, abuf);
    k_conv<<<ROWS, CONVD/4, 0, stream>>>(zx, conv_w, conv_b, convo);

    k_chunk_state<<<BATCH*NH*NCH, 256, 0, stream>>>(convo, dtb, abuf, Sb, Pbuf);
    k_state_pass <<<BATCH*NH, 256, 0, stream>>>(Sb, Pbuf);
    k_chunk_out  <<<BATCH*NH*NCH, 256, 0, stream>>>(convo, dtb, abuf, Sb, Dp, ybuf);

    k_gate<<<ROWS, 256, 0, stream>>>(zx, ybuf, norm_w, gb);

    // out_proj: M=2048 (BM=64), N=512 (BN=64), K=1024
    k_gemm<64,64,1024><<<dim3(DM/64, ROWS/64), 256, 0, stream>>>(gb, Wob, out, DM, DM);
}

// Round 4
// 91.229 us; speedup vs baseline: 9.2455x; 1.3792x over previous
//
#include <hip/hip_runtime.h>
#include <math.h>

#define BATCH 2
#define SEQ 1024
#define DM 512
#define DI 1024
#define DS 128
#define NH 16
#define HD 64
#define CONVD 1280
#define DPROJ 2320
#define ROWS (BATCH*SEQ)   // 2048
#define NCH 16             // chunks per sequence
#define CHK 64             // chunk length
#define NPAD 2432          // in_proj N padded to 19*128

typedef unsigned short u16;
typedef unsigned int   u32;
typedef u16   u16x4 __attribute__((ext_vector_type(4)));
typedef u16   u16x8 __attribute__((ext_vector_type(8)));
typedef short bf16x8 __attribute__((ext_vector_type(8)));
typedef float f32x4 __attribute__((ext_vector_type(4)));

__device__ __forceinline__ u16 f2bf(float f) {
    u32 u = __float_as_uint(f);
    return (u16)((u + 0x7fffu + ((u >> 16) & 1u)) >> 16);
}
__device__ __forceinline__ float bf2f(u16 h) {
    return __uint_as_float(((u32)h) << 16);
}
__device__ __forceinline__ void gl_lds16(const u16* g, u16* lds) {
    __builtin_amdgcn_global_load_lds((const __attribute__((address_space(1))) void*)g,
                                     (__attribute__((address_space(3))) void*)lds,
                                     16, 0, 0);
}

// swizzled LDS tile: rows x SLROW slots of 8 u16; physical slot = q ^ (row&7)
__device__ __forceinline__ int swz_off(int row, int q, int SLROW) {
    return (row*SLROW + (q ^ (row & 7)))*8;
}
// stage 64 rows x SLROW slots from global (rows gstride u16 apart) into linear LDS
template<int SLROW>
__device__ __forceinline__ void stage64(const u16* gbase, int gstride, u16* lds, int tid) {
    #pragma unroll
    for (int j = 0; j < (64*SLROW)/256; ++j) {
        int slot = j*256 + tid;
        int row = slot / SLROW;
        int pos = slot % SLROW;
        gl_lds16(gbase + (size_t)row*gstride + (pos ^ (row & 7))*8, lds + slot*8);
    }
}

// ---------------- prep: fp32->bf16 conversions + exact-fp32 dt ----------------
__device__ __forceinline__ void cvt_blk(const float* __restrict__ src,
                                        u16* __restrict__ dst,
                                        int blk, int n_src, int n_total) {
    int idx = (blk*256 + threadIdx.x)*8;
    if (idx >= n_total) return;
    u16x8 o;
    if (idx + 8 <= n_src) {
        float4 a = *reinterpret_cast<const float4*>(src + idx);
        float4 b = *reinterpret_cast<const float4*>(src + idx + 4);
        o[0]=f2bf(a.x); o[1]=f2bf(a.y); o[2]=f2bf(a.z); o[3]=f2bf(a.w);
        o[4]=f2bf(b.x); o[5]=f2bf(b.y); o[6]=f2bf(b.z); o[7]=f2bf(b.w);
    } else {
        #pragma unroll
        for (int e = 0; e < 8; ++e)
            o[e] = (idx + e < n_src) ? f2bf(src[idx + e]) : (u16)0;
    }
    *reinterpret_cast<u16x8*>(dst + idx) = o;
}

__global__ __launch_bounds__(256) void k_prep(const float* __restrict__ x,
                                              const float* __restrict__ W,
                                              const float* __restrict__ Wo,
                                              const float* __restrict__ dt_bias,
                                              const float* __restrict__ A_log,
                                              u16* __restrict__ xb,
                                              u16* __restrict__ Wb,
                                              u16* __restrict__ Wob,
                                              float* __restrict__ dtb,
                                              float* __restrict__ abuf) {
    int bid = blockIdx.x;
    if (bid < 512) { cvt_blk(x, xb, bid, ROWS*DM, ROWS*DM); return; }
    if (bid < 1120) { cvt_blk(W, Wb, bid-512, DPROJ*DM, NPAD*DM); return; }
    if (bid < 1376) { cvt_blk(Wo, Wob, bid-1120, DM*DI, DM*DI); return; }
    // dt: exact fp32 dot x . W_dt[h]
    int wave = threadIdx.x >> 6, lane = threadIdx.x & 63;
    int row = (bid-1376)*4 + wave;
    int h = lane & 15, part = lane >> 4;
    const float* xr = x + (size_t)row * DM + part*128;
    const float* wr = W + (size_t)(DI + CONVD + h) * DM + part*128;
    float acc = 0.f;
    #pragma unroll 4
    for (int j = 0; j < 32; ++j) {
        float4 xv = *reinterpret_cast<const float4*>(xr + j*4);
        float4 wv = *reinterpret_cast<const float4*>(wr + j*4);
        acc += xv.x*wv.x + xv.y*wv.y + xv.z*wv.z + xv.w*wv.w;
    }
    acc += __shfl_xor(acc, 16);
    acc += __shfl_xor(acc, 32);
    if (part == 0) {
        float v = acc + dt_bias[h];
        float dt = (v > 20.f) ? v : log1pf(expf(v));
        dtb[row*NH + h]  = dt;
        abuf[row*NH + h] = dt * (-expf(A_log[h]));
    }
}

// ---------------- MFMA GEMM: C[m][n] = sum_k A[m][k]*B[n][k] ----------------
template<int BM, int BN, int K, bool BF16OUT>
__global__ __launch_bounds__(256) void k_gemm(const u16* __restrict__ A,
                                              const u16* __restrict__ B,
                                              void* __restrict__ Cv,
                                              int ldc, int ncols) {
    constexpr int WTM = BM/2, WTN = BN/2, FM = WTM/16, FN = WTN/16;
    constexpr int CA = BM*4/256, CB = BN*4/256;
    __shared__ u16 As[BM*32];
    __shared__ u16 Bs[BN*32];
    int tid  = threadIdx.x;
    int lane = tid & 63, wave = tid >> 6;
    int wr = wave >> 1, wc = wave & 1;
    size_t bm = (size_t)blockIdx.y * BM, bn = (size_t)blockIdx.x * BN;

    const u16* srcA[CA]; u16* dstA[CA];
    #pragma unroll
    for (int j = 0; j < CA; ++j) {
        int i = j*256 + tid;
        int row = i >> 2, q = (i & 3) ^ ((row >> 1) & 3);
        srcA[j] = A + (bm + row) * (size_t)K + q*8;
        dstA[j] = As + i*8;
    }
    const u16* srcB[CB]; u16* dstB[CB];
    #pragma unroll
    for (int j = 0; j < CB; ++j) {
        int i = j*256 + tid;
        int row = i >> 2, q = (i & 3) ^ ((row >> 1) & 3);
        srcB[j] = B + (bn + row) * (size_t)K + q*8;
        dstB[j] = Bs + i*8;
    }

    int kq = lane >> 4;
    int aoff[FM], boff[FN];
    #pragma unroll
    for (int fi = 0; fi < FM; ++fi) {
        int row = wr*WTM + fi*16 + (lane & 15);
        aoff[fi] = (row*4 + (kq ^ ((row >> 1) & 3))) * 8;
    }
    #pragma unroll
    for (int fj = 0; fj < FN; ++fj) {
        int row = wc*WTN + fj*16 + (lane & 15);
        boff[fj] = (row*4 + (kq ^ ((row >> 1) & 3))) * 8;
    }

    f32x4 acc[FM][FN];
    #pragma unroll
    for (int fi = 0; fi < FM; ++fi)
        #pragma unroll
        for (int fj = 0; fj < FN; ++fj)
            acc[fi][fj] = (f32x4){0.f, 0.f, 0.f, 0.f};

    for (int k0 = 0; k0 < K; k0 += 32) {
        __syncthreads();
        #pragma unroll
        for (int j = 0; j < CA; ++j) gl_lds16(srcA[j] + k0, dstA[j]);
        #pragma unroll
        for (int j = 0; j < CB; ++j) gl_lds16(srcB[j] + k0, dstB[j]);
        __syncthreads();
        bf16x8 av[FM], bv[FN];
        #pragma unroll
        for (int fi = 0; fi < FM; ++fi)
            av[fi] = *reinterpret_cast<const bf16x8*>(As + aoff[fi]);
        #pragma unroll
        for (int fj = 0; fj < FN; ++fj)
            bv[fj] = *reinterpret_cast<const bf16x8*>(Bs + boff[fj]);
        #pragma unroll
        for (int fi = 0; fi < FM; ++fi)
            #pragma unroll
            for (int fj = 0; fj < FN; ++fj)
                acc[fi][fj] = __builtin_amdgcn_mfma_f32_16x16x32_bf16(
                    av[fi], bv[fj], acc[fi][fj], 0, 0, 0);
    }

    #pragma unroll
    for (int fi = 0; fi < FM; ++fi) {
        size_t grow0 = bm + wr*WTM + fi*16 + (lane >> 4)*4;
        #pragma unroll
        for (int fj = 0; fj < FN; ++fj) {
            size_t gcol = bn + wc*WTN + fj*16 + (lane & 15);
            if ((int)gcol < ncols) {
                #pragma unroll
                for (int r = 0; r < 4; ++r) {
                    if constexpr (BF16OUT)
                        ((u16*)Cv)[(grow0 + r)*ldc + gcol] = f2bf(acc[fi][fj][r]);
                    else
                        ((float*)Cv)[(grow0 + r)*ldc + gcol] = acc[fi][fj][r];
                }
            }
        }
    }
}

// ---------------- depthwise conv + SiLU (bf16 in/out) ----------------
__global__ __launch_bounds__(320) void k_conv(const u16* __restrict__ zx,
                                              const float* __restrict__ cw,
                                              const float* __restrict__ cb,
                                              u16* __restrict__ convo) {
    int row = blockIdx.x;            // b*SEQ + l
    int l   = row & (SEQ-1);
    int c0  = threadIdx.x * 4;

    const float4* cw4 = reinterpret_cast<const float4*>(cw);
    float4 w0 = cw4[c0+0], w1 = cw4[c0+1], w2 = cw4[c0+2], w3 = cw4[c0+3];
    const float* wa0 = &w0.x; const float* wa1 = &w1.x;
    const float* wa2 = &w2.x; const float* wa3 = &w3.x;

    float4 bv = *reinterpret_cast<const float4*>(cb + c0);
    float acc0 = bv.x, acc1 = bv.y, acc2 = bv.z, acc3 = bv.w;

    #pragma unroll
    for (int k = 0; k < 4; ++k) {
        int lk = l - 3 + k;
        if (lk < 0) continue;
        u16x4 v = *reinterpret_cast<const u16x4*>(zx + (size_t)(row-3+k)*DPROJ + DI + c0);
        acc0 += bf2f(v[0]) * wa0[k];
        acc1 += bf2f(v[1]) * wa1[k];
        acc2 += bf2f(v[2]) * wa2[k];
        acc3 += bf2f(v[3]) * wa3[k];
    }
    u16x4 o;
    o[0] = f2bf(acc0 / (1.f + expf(-acc0)));
    o[1] = f2bf(acc1 / (1.f + expf(-acc1)));
    o[2] = f2bf(acc2 / (1.f + expf(-acc2)));
    o[3] = f2bf(acc3 / (1.f + expf(-acc3)));
    *reinterpret_cast<u16x4*>(convo + (size_t)row*CONVD + c0) = o;
}

// ---------------- chunk state via MFMA: S[p][n] = sum_t coef_t*xs[t,p]*B[t,n] ----------------
__global__ __launch_bounds__(256) void k_chunk_state(
    const u16* __restrict__ convo, const float* __restrict__ dtb,
    const float* __restrict__ abuf, u16* __restrict__ Sb,
    float* __restrict__ Pbuf) {
    int blk = blockIdx.x;                 // c + NCH*(h + NH*b)
    int c  = blk & (NCH-1);
    int h  = (blk >> 4) & (NH-1);
    int b  = blk >> 8;
    int row0 = b*SEQ + c*CHK;
    int tid = threadIdx.x, lane = tid & 63, wave = tid >> 6;
    int wr = wave >> 1, wc = wave & 1;

    __shared__ u16 xsT[64*64];     // rows p, k=t, SLROW=8
    __shared__ u16 BT[128*64];     // rows n, k=t, SLROW=8
    __shared__ float s_coef[CHK];

    int st = tid >> 2, q = tid & 3;
    const u16* r = convo + (size_t)(row0 + st)*CONVD;
    u16x8 xa = *reinterpret_cast<const u16x8*>(r + h*HD + q*16);
    u16x8 xc = *reinterpret_cast<const u16x8*>(r + h*HD + q*16 + 8);
    u16x8 b0 = *reinterpret_cast<const u16x8*>(r + DI + q*32);
    u16x8 b1 = *reinterpret_cast<const u16x8*>(r + DI + q*32 + 8);
    u16x8 b2 = *reinterpret_cast<const u16x8*>(r + DI + q*32 + 16);
    u16x8 b3 = *reinterpret_cast<const u16x8*>(r + DI + q*32 + 24);

    if (tid < CHK) {
        float v = abuf[(size_t)(row0 + tid)*NH + h];
        #pragma unroll
        for (int off = 1; off < 64; off <<= 1) {
            float o = __shfl_up(v, off);
            if (tid >= off) v += o;
        }
        float vend = __shfl(v, 63);
        float dt = dtb[(size_t)(row0 + tid)*NH + h];
        s_coef[tid] = dt * expf(vend - v);
        if (tid == 63) Pbuf[blk] = expf(vend);
    }
    __syncthreads();

    float cf = s_coef[st];
    #pragma unroll
    for (int e = 0; e < 16; ++e) {
        int p = q*16 + e;
        u16 xv = (e < 8) ? xa[e] : xc[e-8];
        xsT[(p*8 + ((st>>3) ^ (p&7)))*8 + (st&7)] = f2bf(cf * bf2f(xv));
    }
    #pragma unroll
    for (int e = 0; e < 32; ++e) {
        int n = q*32 + e;
        u16 bvv = (e < 8) ? b0[e] : (e < 16) ? b1[e-8] : (e < 24) ? b2[e-16] : b3[e-24];
        BT[(n*8 + ((st>>3) ^ (n&7)))*8 + (st&7)] = bvv;
    }
    __syncthreads();

    int kq = lane >> 4, fr = lane & 15;
    f32x4 acc[2][4];
    #pragma unroll
    for (int fi = 0; fi < 2; ++fi)
        #pragma unroll
        for (int fj = 0; fj < 4; ++fj)
            acc[fi][fj] = (f32x4){0.f,0.f,0.f,0.f};

    #pragma unroll
    for (int ks = 0; ks < 2; ++ks) {
        bf16x8 av[2], bv[4];
        #pragma unroll
        for (int fi = 0; fi < 2; ++fi)
            av[fi] = *reinterpret_cast<const bf16x8*>(xsT + swz_off(wr*32 + fi*16 + fr, ks*4 + kq, 8));
        #pragma unroll
        for (int fj = 0; fj < 4; ++fj)
            bv[fj] = *reinterpret_cast<const bf16x8*>(BT + swz_off(wc*64 + fj*16 + fr, ks*4 + kq, 8));
        #pragma unroll
        for (int fi = 0; fi < 2; ++fi)
            #pragma unroll
            for (int fj = 0; fj < 4; ++fj)
                acc[fi][fj] = __builtin_amdgcn_mfma_f32_16x16x32_bf16(av[fi], bv[fj], acc[fi][fj], 0,0,0);
    }

    u16* outp = Sb + (size_t)blk*(HD*DS);
    #pragma unroll
    for (int fi = 0; fi < 2; ++fi)
        #pragma unroll
        for (int rr = 0; rr < 4; ++rr) {
            int p = wr*32 + fi*16 + kq*4 + rr;
            #pragma unroll
            for (int fj = 0; fj < 4; ++fj) {
                int n = wc*64 + fj*16 + fr;
                outp[(size_t)p*DS + n] = f2bf(acc[fi][fj][rr]);
            }
        }
}

// ---------------- sequential pass over chunks (bf16 in place S -> h_in) ----------------
__global__ __launch_bounds__(256) void k_state_pass(u16* __restrict__ Sb,
                                                    const float* __restrict__ Pbuf) {
    int bh = blockIdx.x;          // h + NH*b
    int off = threadIdx.x * 32;
    float hr[32];
    #pragma unroll
    for (int j = 0; j < 32; ++j) hr[j] = 0.f;

    for (int c = 0; c < NCH; ++c) {
        u16* base = Sb + ((size_t)(bh*NCH + c))*(HD*DS) + off;
        float P = Pbuf[bh*NCH + c];
        float s[32];
        #pragma unroll
        for (int j = 0; j < 4; ++j) {
            u16x8 v = *reinterpret_cast<const u16x8*>(base + j*8);
            #pragma unroll
            for (int e = 0; e < 8; ++e) s[j*8+e] = bf2f(v[e]);
        }
        #pragma unroll
        for (int j = 0; j < 4; ++j) {
            u16x8 w;
            #pragma unroll
            for (int e = 0; e < 8; ++e) w[e] = f2bf(hr[j*8+e]);
            *reinterpret_cast<u16x8*>(base + j*8) = w;
        }
        #pragma unroll
        for (int j = 0; j < 32; ++j) hr[j] = hr[j]*P + s[j];
    }
}

// ---------------- chunk output via MFMA ----------------
__global__ __launch_bounds__(256) void k_chunk_out(
    const u16* __restrict__ convo, const float* __restrict__ dtb,
    const float* __restrict__ abuf, const u16* __restrict__ Sb,
    const float* __restrict__ Dp, u16* __restrict__ ybuf) {
    int blk = blockIdx.x;
    int c  = blk & (NCH-1);
    int h  = (blk >> 4) & (NH-1);
    int b  = blk >> 8;
    int row0 = b*SEQ + c*CHK;
    int tid = threadIdx.x, lane = tid & 63, wave = tid >> 6;
    int wr = wave >> 1, wc = wave & 1;

    __shared__ u16 Ct[64*128];     // C rows t, k=n, SLROW=16
    __shared__ u16 Bh[64*128];     // B rows s (phase B) then hin rows p (phase D)
    __shared__ u16 Mt[64*64];      // M' rows t, k=s, SLROW=8
    __shared__ u16 dxT[64*64];     // xs rows p, k=s, SLROW=8
    __shared__ float s_cum[CHK];
    __shared__ float s_dt[CHK];

    const u16* cbase = convo + (size_t)row0*CONVD;

    stage64<16>(cbase + DI + DS, CONVD, Ct, tid);
    stage64<16>(cbase + DI,      CONVD, Bh, tid);

    int st = tid >> 2, q = tid & 3;
    u16x8 xr0 = *reinterpret_cast<const u16x8*>(cbase + (size_t)st*CONVD + h*HD + q*16);
    u16x8 xr1 = *reinterpret_cast<const u16x8*>(cbase + (size_t)st*CONVD + h*HD + q*16 + 8);

    if (tid < CHK) {
        float v = abuf[(size_t)(row0 + tid)*NH + h];
        #pragma unroll
        for (int off = 1; off < 64; off <<= 1) {
            float o = __shfl_up(v, off);
            if (tid >= off) v += o;
        }
        s_cum[tid] = v;
        s_dt[tid] = dtb[(size_t)(row0 + tid)*NH + h];
    }
    __syncthreads();   // B1: Ct/Bh staged, cum/dt ready

    // scatter dxT (raw xs; dt folded into M')
    #pragma unroll
    for (int e = 0; e < 16; ++e) {
        int p = q*16 + e;
        u16 xv = (e < 8) ? xr0[e] : xr1[e-8];
        dxT[(p*8 + ((st>>3) ^ (p&7)))*8 + (st&7)] = xv;
    }

    int kq = lane >> 4, fr = lane & 15;

    // phase B: M[t][s] = C_t . B_s (K=128)
    f32x4 macc[2][2];
    #pragma unroll
    for (int fi = 0; fi < 2; ++fi)
        #pragma unroll
        for (int fj = 0; fj < 2; ++fj)
            macc[fi][fj] = (f32x4){0.f,0.f,0.f,0.f};
    #pragma unroll
    for (int ks = 0; ks < 4; ++ks) {
        bf16x8 av[2], bv[2];
        #pragma unroll
        for (int fi = 0; fi < 2; ++fi)
            av[fi] = *reinterpret_cast<const bf16x8*>(Ct + swz_off(wr*32 + fi*16 + fr, ks*4 + kq, 16));
        #pragma unroll
        for (int fj = 0; fj < 2; ++fj)
            bv[fj] = *reinterpret_cast<const bf16x8*>(Bh + swz_off(wc*32 + fj*16 + fr, ks*4 + kq, 16));
        #pragma unroll
        for (int fi = 0; fi < 2; ++fi)
            #pragma unroll
            for (int fj = 0; fj < 2; ++fj)
                macc[fi][fj] = __builtin_amdgcn_mfma_f32_16x16x32_bf16(av[fi], bv[fj], macc[fi][fj], 0,0,0);
    }

    // mask + decay + dt-fold, scatter M' (bf16)
    #pragma unroll
    for (int fi = 0; fi < 2; ++fi)
        #pragma unroll
        for (int rr = 0; rr < 4; ++rr) {
            int t = wr*32 + fi*16 + kq*4 + rr;
            float cumt = s_cum[t];
            #pragma unroll
            for (int fj = 0; fj < 2; ++fj) {
                int s = wc*32 + fj*16 + fr;
                float val = (s <= t) ? macc[fi][fj][rr] * expf(cumt - s_cum[s]) * s_dt[s] : 0.f;
                Mt[(t*8 + ((s>>3) ^ (t&7)))*8 + (s&7)] = f2bf(val);
            }
        }
    __syncthreads();   // B2: Mt/dxT complete, Bh consumed

    // stage hin into Bh (rows p, k=n)
    stage64<16>(Sb + (size_t)blk*(HD*DS), DS, Bh, tid);

    // phase C: Y[t][p] = sum_s M'[t][s]*xs[s][p]  (K=64)
    f32x4 accY[2][2];
    #pragma unroll
    for (int fi = 0; fi < 2; ++fi)
        #pragma unroll
        for (int fj = 0; fj < 2; ++fj)
            accY[fi][fj] = (f32x4){0.f,0.f,0.f,0.f};
    #pragma unroll
    for (int ks = 0; ks < 2; ++ks) {
        bf16x8 av[2], bv[2];
        #pragma unroll
        for (int fi = 0; fi < 2; ++fi)
            av[fi] = *reinterpret_cast<const bf16x8*>(Mt + swz_off(wr*32 + fi*16 + fr, ks*4 + kq, 8));
        #pragma unroll
        for (int fj = 0; fj < 2; ++fj)
            bv[fj] = *reinterpret_cast<const bf16x8*>(dxT + swz_off(wc*32 + fj*16 + fr, ks*4 + kq, 8));
        #pragma unroll
        for (int fi = 0; fi < 2; ++fi)
            #pragma unroll
            for (int fj = 0; fj < 2; ++fj)
                accY[fi][fj] = __builtin_amdgcn_mfma_f32_16x16x32_bf16(av[fi], bv[fj], accY[fi][fj], 0,0,0);
    }
    __syncthreads();   // B3: hin staged

    // phase D: cross[t][p] = C_t . hin[p]  (K=128)
    f32x4 accD[2][2];
    #pragma unroll
    for (int fi = 0; fi < 2; ++fi)
        #pragma unroll
        for (int fj = 0; fj < 2; ++fj)
            accD[fi][fj] = (f32x4){0.f,0.f,0.f,0.f};
    #pragma unroll
    for (int ks = 0; ks < 4; ++ks) {
        bf16x8 av[2], bv[2];
        #pragma unroll
        for (int fi = 0; fi < 2; ++fi)
            av[fi] = *reinterpret_cast<const bf16x8*>(Ct + swz_off(wr*32 + fi*16 + fr, ks*4 + kq, 16));
        #pragma unroll
        for (int fj = 0; fj < 2; ++fj)
            bv[fj] = *reinterpret_cast<const bf16x8*>(Bh + swz_off(wc*32 + fj*16 + fr, ks*4 + kq, 16));
        #pragma unroll
        for (int fi = 0; fi < 2; ++fi)
            #pragma unroll
            for (int fj = 0; fj < 2; ++fj)
                accD[fi][fj] = __builtin_amdgcn_mfma_f32_16x16x32_bf16(av[fi], bv[fj], accD[fi][fj], 0,0,0);
    }

    // epilogue: y = Y + e^{cum_t}*cross + D*xs
    float Dv = Dp[h];
    #pragma unroll
    for (int fi = 0; fi < 2; ++fi)
        #pragma unroll
        for (int rr = 0; rr < 4; ++rr) {
            int t = wr*32 + fi*16 + kq*4 + rr;
            float et = expf(s_cum[t]);
            #pragma unroll
            for (int fj = 0; fj < 2; ++fj) {
                int p = wc*32 + fj*16 + fr;
                float xs = bf2f(cbase[(size_t)t*CONVD + h*HD + p]);
                float y = accY[fi][fj][rr] + et*accD[fi][fj][rr] + Dv*xs;
                ybuf[(size_t)(row0 + t)*DI + h*HD + p] = f2bf(y);
            }
        }
}

// ---------------- gate + RMSNorm (bf16 in, bf16 out) ----------------
__global__ __launch_bounds__(256) void k_gate(const u16* __restrict__ zx,
                                              const u16* __restrict__ ybuf,
                                              const float* __restrict__ nw,
                                              u16* __restrict__ g) {
    int row = blockIdx.x;
    int t = threadIdx.x;
    const u16* zr = zx + (size_t)row*DPROJ;
    const u16* yr = ybuf + (size_t)row*DI;

    u16x4 zv = *reinterpret_cast<const u16x4*>(zr + t*4);
    u16x4 yv = *reinterpret_cast<const u16x4*>(yr + t*4);
    float gv[4];
    float ss = 0.f;
    #pragma unroll
    for (int j = 0; j < 4; ++j) {
        float z = bf2f(zv[j]), y = bf2f(yv[j]);
        float sz = z / (1.f + expf(-z));
        float gg = y * sz;
        gv[j] = gg;
        ss += gg*gg;
    }
    ss += __shfl_xor(ss, 1);
    ss += __shfl_xor(ss, 2);
    ss += __shfl_xor(ss, 4);
    ss += __shfl_xor(ss, 8);
    ss += __shfl_xor(ss, 16);
    ss += __shfl_xor(ss, 32);
    __shared__ float ls[4];
    if ((t & 63) == 0) ls[t >> 6] = ss;
    __syncthreads();
    float tot = ls[0] + ls[1] + ls[2] + ls[3];
    float scale = rsqrtf(tot * (1.f/DI) + 1e-5f);

    float4 nv = *reinterpret_cast<const float4*>(nw + t*4);
    const float* na = &nv.x;
    u16x4 og = { f2bf(gv[0]*scale*na[0]), f2bf(gv[1]*scale*na[1]),
                 f2bf(gv[2]*scale*na[2]), f2bf(gv[3]*scale*na[3]) };
    *reinterpret_cast<u16x4*>(g + (size_t)row*DI + t*4) = og;
}

extern "C" void kernel_launch(void* const* d_in, const int* in_sizes, int n_in,
                              void* d_out, int out_size, void* d_ws, size_t ws_size,
                              hipStream_t stream) {
    const float* x         = (const float*)d_in[0];
    const float* in_proj_w = (const float*)d_in[1];
    const float* conv_w    = (const float*)d_in[2];
    const float* conv_b    = (const float*)d_in[3];
    const float* dt_bias   = (const float*)d_in[4];
    const float* A_log     = (const float*)d_in[5];
    const float* Dp        = (const float*)d_in[6];
    const float* norm_w    = (const float*)d_in[7];
    const float* out_proj_w= (const float*)d_in[8];
    float* out = (float*)d_out;

    char* p = (char*)d_ws;
    u16*   zxb   = (u16*)p;   p += (size_t)ROWS*DPROJ*2;       // 9.5 MB
    u16*   convo = (u16*)p;   p += (size_t)ROWS*CONVD*2;       // 5.25 MB
    float* dtb   = (float*)p; p += (size_t)ROWS*NH*4;
    float* abuf  = (float*)p; p += (size_t)ROWS*NH*4;
    u16*   ybuf  = (u16*)p;   p += (size_t)ROWS*DI*2;          // 4 MB
    u16*   xb    = (u16*)p;   p += (size_t)ROWS*DM*2;          // 2 MB
    u16*   Wb    = (u16*)p;   p += (size_t)NPAD*DM*2;          // 2.4 MB
    u16*   Wob   = (u16*)p;   p += (size_t)DM*DI*2;            // 1 MB
    u16*   Sb    = (u16*)p;   p += (size_t)BATCH*NH*NCH*HD*DS*2; // 8 MB
    float* Pbuf  = (float*)p; p += 512*4;
    u16*   gb    = (u16*)p;   p += (size_t)ROWS*DI*2;          // 4 MB

    k_prep<<<1888, 256, 0, stream>>>(x, in_proj_w, out_proj_w, dt_bias, A_log,
                                     xb, Wb, Wob, dtb, abuf);

    k_gemm<64,128,512,true><<<dim3(NPAD/128, ROWS/64), 256, 0, stream>>>(xb, Wb, zxb, DPROJ, DPROJ);

    k_conv<<<ROWS, CONVD/4, 0, stream>>>(zxb, conv_w, conv_b, convo);

    k_chunk_state<<<BATCH*NH*NCH, 256, 0, stream>>>(convo, dtb, abuf, Sb, Pbuf);
    k_state_pass <<<BATCH*NH, 256, 0, stream>>>(Sb, Pbuf);
    k_chunk_out  <<<BATCH*NH*NCH, 256, 0, stream>>>(convo, dtb, abuf, Sb, Dp, ybuf);

    k_gate<<<ROWS, 256, 0, stream>>>(zxb, ybuf, norm_w, gb);

    k_gemm<64,64,1024,false><<<dim3(DM/64, ROWS/64), 256, 0, stream>>>(gb, Wob, out, DM, DM);
}